// Round 3
// baseline (148.595 us; speedup 1.0000x reference)
//
#include <hip/hip_runtime.h>
#include <math.h>

// Single-query attention, N=128, T=2048, D=512, fp32, length-masked.
// Masked positions (t >= len): energy -1e9 -> expf == 0.0f exactly -> skip
// reading K/V there. E[len] ~ T/2 -> ~50% of the 1 GB K+V traffic.
//
// R3: TCHUNK 128 -> 32 (8192 blocks) so the block scheduler can refill CUs
// (work-conserving balance; at 2048 all-resident blocks the max-loaded CU set
// the runtime). PV phase now float4/lane. Partials combined in kernel 2.

#define N_DIM 128
#define T_DIM 2048
#define D_DIM 512
#define NCHUNK 64
#define TCHUNK 32   // T_DIM / NCHUNK
#define CSHIFT 6    // log2(NCHUNK)

__global__ __launch_bounds__(256) void fused_attn_kernel(
    const float* __restrict__ Q, const float* __restrict__ K,
    const float* __restrict__ V, const int* __restrict__ lens,
    float* __restrict__ mask_out, float* __restrict__ part,
    float* __restrict__ ms) {
  const int n = blockIdx.x >> CSHIFT;
  const int c = blockIdx.x & (NCHUNK - 1);
  const int tid = threadIdx.x;
  const int lane = tid & 63;
  const int wave = tid >> 6;
  const int len = lens[n];
  const int t0 = c * TCHUNK;

  // Mask floats for this chunk: 32 values -> 8 threads x float4, coalesced.
  if (tid < TCHUNK / 4) {
    const int tb = t0 + tid * 4;
    float4 mv;
    mv.x = (tb + 0 >= len) ? 1.0f : 0.0f;
    mv.y = (tb + 1 >= len) ? 1.0f : 0.0f;
    mv.z = (tb + 2 >= len) ? 1.0f : 0.0f;
    mv.w = (tb + 3 >= len) ? 1.0f : 0.0f;
    ((float4*)(mask_out + (size_t)n * T_DIM + t0))[tid] = mv;
  }
  if (t0 >= len) return;  // fully masked chunk: zero K/V traffic
  const int nvalid = min(TCHUNK, len - t0);

  __shared__ float e[TCHUNK];       // energies -> unnormalized weights
  __shared__ float4 hbuf[128];      // PV half-block combine

  // ---- Energy: one wave per t; lane i covers d = 4i..4i+3 and 256+4i..+3.
  const float4* Qv = (const float4*)(Q + (size_t)n * D_DIM);
  const float4 q0 = Qv[lane];
  const float4 q1 = Qv[64 + lane];
  for (int tt = wave; tt < nvalid; tt += 4) {
    const float4* Kv = (const float4*)(K + ((size_t)n * T_DIM + t0 + tt) * D_DIM);
    const float4 k0 = Kv[lane];
    const float4 k1 = Kv[64 + lane];
    float s = q0.x * k0.x + q0.y * k0.y + q0.z * k0.z + q0.w * k0.w +
              q1.x * k1.x + q1.y * k1.y + q1.z * k1.z + q1.w * k1.w;
#pragma unroll
    for (int off = 32; off; off >>= 1) s += __shfl_xor(s, off, 64);
    if (lane == 0) e[tt] = s;
  }
  __syncthreads();

  // ---- Local softmax (wave 0 only; TCHUNK=32 values).
  if (wave == 0) {
    const float ev = (lane < nvalid) ? e[lane] : -INFINITY;
    float m = ev;
#pragma unroll
    for (int off = 32; off; off >>= 1) m = fmaxf(m, __shfl_xor(m, off, 64));
    const float p = (lane < nvalid) ? __expf(ev - m) : 0.0f;
    if (lane < TCHUNK) e[lane] = p;
    float s = p;
#pragma unroll
    for (int off = 32; off; off >>= 1) s += __shfl_xor(s, off, 64);
    if (lane == 0) {
      ms[(n * NCHUNK + c) * 2 + 0] = m;
      ms[(n * NCHUNK + c) * 2 + 1] = s;
    }
  }
  __syncthreads();

  // ---- PV: half-block h covers rows h, h+2, ...; thread owns float4 of D.
  const int h = tid >> 7;          // 0 or 1
  const int dq = tid & 127;        // float4 index over D/4 = 128
  float4 acc = make_float4(0.0f, 0.0f, 0.0f, 0.0f);
  const float4* Vv = (const float4*)(V + ((size_t)n * T_DIM + t0) * D_DIM);
#pragma unroll 4
  for (int tt = h; tt < nvalid; tt += 2) {
    const float4 v = Vv[(size_t)tt * (D_DIM / 4) + dq];
    const float w = e[tt];
    acc.x = fmaf(w, v.x, acc.x);
    acc.y = fmaf(w, v.y, acc.y);
    acc.z = fmaf(w, v.z, acc.z);
    acc.w = fmaf(w, v.w, acc.w);
  }
  if (h == 0) hbuf[dq] = acc;
  __syncthreads();
  if (h == 1) {
    const float4 o = hbuf[dq];
    acc.x += o.x; acc.y += o.y; acc.z += o.z; acc.w += o.w;
    ((float4*)(part + (size_t)(n * NCHUNK + c) * D_DIM))[dq] = acc;
  }
}

// Combine per-chunk partials: M = max m_c, S = sum s_c*exp(m_c-M),
// ctx = sum_c part_c * exp(m_c-M) / S. Only chunks below len exist.
__global__ __launch_bounds__(256) void ctx_combine_kernel(
    const float* __restrict__ part, const float* __restrict__ ms,
    const int* __restrict__ lens, float* __restrict__ ctx) {
  const int n = blockIdx.x;
  const int tid = threadIdx.x;
  const int len = lens[n];
  const int nc = (len + TCHUNK - 1) / TCHUNK;  // >= 1

  float M = -INFINITY;
  for (int c = 0; c < nc; ++c) M = fmaxf(M, ms[(n * NCHUNK + c) * 2]);
  float S = 0.0f;
  for (int c = 0; c < nc; ++c)
    S += ms[(n * NCHUNK + c) * 2 + 1] * __expf(ms[(n * NCHUNK + c) * 2] - M);
  const float invS = 1.0f / S;

  float2 acc = make_float2(0.0f, 0.0f);
  for (int c = 0; c < nc; ++c) {
    const float sc = __expf(ms[(n * NCHUNK + c) * 2] - M) * invS;
    const float2 p = ((const float2*)(part + (size_t)(n * NCHUNK + c) * D_DIM))[tid];
    acc.x = fmaf(sc, p.x, acc.x);
    acc.y = fmaf(sc, p.y, acc.y);
  }
  ((float2*)(ctx + (size_t)n * D_DIM))[tid] = acc;
}

extern "C" void kernel_launch(void* const* d_in, const int* in_sizes, int n_in,
                              void* d_out, int out_size, void* d_ws, size_t ws_size,
                              hipStream_t stream) {
  const float* Q = (const float*)d_in[0];     // [128][512]
  const float* K = (const float*)d_in[1];     // [128][2048][512]
  const float* V = (const float*)d_in[2];     // [128][2048][512]
  const int* lens = (const int*)d_in[3];      // [128]

  float* out = (float*)d_out;
  float* ctx = out;                           // [128][512]
  float* mask_out = out + N_DIM * D_DIM;      // [128][2048]

  float* part = (float*)d_ws;                 // [128][64][512] (16 MB)
  float* ms = part + (size_t)N_DIM * NCHUNK * D_DIM;  // [128][64][2]

  fused_attn_kernel<<<dim3(N_DIM * NCHUNK), 256, 0, stream>>>(
      Q, K, V, lens, mask_out, part, ms);
  ctx_combine_kernel<<<dim3(N_DIM), 256, 0, stream>>>(part, ms, lens, ctx);
}

// Round 4
// 130.949 us; speedup vs baseline: 1.1348x; 1.1348x over previous
//
#include <hip/hip_runtime.h>
#include <math.h>

// Single-query attention, N=128, T=2048, D=512, fp32, length-masked.
// Masked t >= len: energy -1e9 -> expf == 0 exactly -> skip K/V reads there.
//
// R4: (1) single-pass per-wave online softmax (K row, dot, (m,s) update,
// V row, acc FMA) -- no intra-block phase barriers, K/V streams interleaved;
// (2) dense work-list via prefix-sum of chunk counts so active blocks are
// dense at the front of the grid (even CU load); (3) dense partials,
// parallel combine that also writes the mask output.

#define N_DIM 128
#define T_DIM 2048
#define D_DIM 512
#define TCHUNK 64
#define NCHUNK 32               // T_DIM / TCHUNK
#define MAXBLK (N_DIM * NCHUNK) // 4096 worst-case chunks

// ---------------------------------------------------------------------------
// Prep: pfx[0..128] = exclusive prefix sum of per-batch chunk counts.
// ---------------------------------------------------------------------------
__global__ __launch_bounds__(128) void prep_kernel(const int* __restrict__ lens,
                                                   int* __restrict__ pfx) {
  __shared__ int s[N_DIM];
  const int tid = threadIdx.x;
  s[tid] = (lens[tid] + TCHUNK - 1) >> 6;
  __syncthreads();
  for (int off = 1; off < N_DIM; off <<= 1) {
    const int t = (tid >= off) ? s[tid - off] : 0;
    __syncthreads();
    s[tid] += t;
    __syncthreads();
  }
  pfx[tid + 1] = s[tid];
  if (tid == 0) pfx[0] = 0;
}

// ---------------------------------------------------------------------------
// Fused: block b < total handles global chunk b -> (n, c) via binary search.
// Wave w owns rows tt = w, w+4, ...  Single-pass online softmax + PV.
// Lane l covers d = {4l..4l+3} and {256+4l..256+4l+3}.
// ---------------------------------------------------------------------------
__global__ __launch_bounds__(256) void fused_attn_kernel(
    const float* __restrict__ Q, const float* __restrict__ K,
    const float* __restrict__ V, const int* __restrict__ lens,
    const int* __restrict__ pfx, float* __restrict__ part,
    float* __restrict__ ms) {
  const int total = pfx[N_DIM];
  const int b = blockIdx.x;
  if (b >= total) return;

  int lo = 0, hi = N_DIM;  // invariant: pfx[lo] <= b < pfx[hi]
  while (hi - lo > 1) {
    const int mid = (lo + hi) >> 1;
    if (pfx[mid] <= b) lo = mid; else hi = mid;
  }
  const int n = lo;
  const int c = b - pfx[lo];
  const int len = lens[n];
  const int t0 = c * TCHUNK;
  const int nvalid = min(TCHUNK, len - t0);  // >= 1 by construction

  const int lane = threadIdx.x & 63;
  const int wave = threadIdx.x >> 6;

  const float4* Qv = (const float4*)(Q + (size_t)n * D_DIM);
  const float4 q0 = Qv[lane];
  const float4 q1 = Qv[64 + lane];

  const float4* Kb = (const float4*)(K + ((size_t)n * T_DIM + t0) * D_DIM);
  const float4* Vb = (const float4*)(V + ((size_t)n * T_DIM + t0) * D_DIM);

  float m = -INFINITY, ssum = 0.0f;
  float4 a0 = make_float4(0.f, 0.f, 0.f, 0.f);
  float4 a1 = make_float4(0.f, 0.f, 0.f, 0.f);

  // Preload first row for this wave (clamped-safe even if wave >= nvalid).
  int ttc = (wave < nvalid) ? wave : 0;
  float4 k0 = Kb[(size_t)ttc * 128 + lane];
  float4 k1 = Kb[(size_t)ttc * 128 + 64 + lane];
  float4 v0 = Vb[(size_t)ttc * 128 + lane];
  float4 v1 = Vb[(size_t)ttc * 128 + 64 + lane];

  for (int tt = wave; tt < nvalid; tt += 4) {
    // Prefetch next row (clamped: last iteration re-reads same row from L1).
    const int tn = (tt + 4 < nvalid) ? tt + 4 : tt;
    const float4 kn0 = Kb[(size_t)tn * 128 + lane];
    const float4 kn1 = Kb[(size_t)tn * 128 + 64 + lane];
    const float4 vn0 = Vb[(size_t)tn * 128 + lane];
    const float4 vn1 = Vb[(size_t)tn * 128 + 64 + lane];

    // Energy: dot(q, k) over D=512, wave-reduce.
    float e = q0.x * k0.x + q0.y * k0.y + q0.z * k0.z + q0.w * k0.w +
              q1.x * k1.x + q1.y * k1.y + q1.z * k1.z + q1.w * k1.w;
#pragma unroll
    for (int off = 32; off; off >>= 1) e += __shfl_xor(e, off, 64);

    // Online softmax update (e is wave-uniform -> uniform branch).
    if (e > m) {
      const float sc = __expf(m - e);  // first iter: expf(-inf)=0
      m = e;
      ssum *= sc;
      a0.x *= sc; a0.y *= sc; a0.z *= sc; a0.w *= sc;
      a1.x *= sc; a1.y *= sc; a1.z *= sc; a1.w *= sc;
    }
    const float p = __expf(e - m);
    ssum += p;
    a0.x = fmaf(p, v0.x, a0.x); a0.y = fmaf(p, v0.y, a0.y);
    a0.z = fmaf(p, v0.z, a0.z); a0.w = fmaf(p, v0.w, a0.w);
    a1.x = fmaf(p, v1.x, a1.x); a1.y = fmaf(p, v1.y, a1.y);
    a1.z = fmaf(p, v1.z, a1.z); a1.w = fmaf(p, v1.w, a1.w);

    k0 = kn0; k1 = kn1; v0 = vn0; v1 = vn1;
  }

  // ---- Cross-wave combine in LDS (one barrier).
  __shared__ float accL[4 * D_DIM];  // [wave][d], 8 KB
  __shared__ float mL[4], sL[4];
  ((float4*)accL)[wave * 128 + lane] = a0;
  ((float4*)accL)[wave * 128 + 64 + lane] = a1;
  if (lane == 0) { mL[wave] = m; sL[wave] = ssum; }
  __syncthreads();

  const float M = fmaxf(fmaxf(mL[0], mL[1]), fmaxf(mL[2], mL[3]));
  const float c0 = __expf(mL[0] - M), c1 = __expf(mL[1] - M);
  const float c2 = __expf(mL[2] - M), c3 = __expf(mL[3] - M);
  const float S = sL[0] * c0 + sL[1] * c1 + sL[2] * c2 + sL[3] * c3;

  const int d = threadIdx.x * 2;
  float2 r;
  r.x = c0 * accL[0 * D_DIM + d] + c1 * accL[1 * D_DIM + d] +
        c2 * accL[2 * D_DIM + d] + c3 * accL[3 * D_DIM + d];
  r.y = c0 * accL[0 * D_DIM + d + 1] + c1 * accL[1 * D_DIM + d + 1] +
        c2 * accL[2 * D_DIM + d + 1] + c3 * accL[3 * D_DIM + d + 1];
  ((float2*)(part + (size_t)b * D_DIM))[threadIdx.x] = r;
  if (threadIdx.x == 0) { ms[b * 2] = M; ms[b * 2 + 1] = S; }
}

// ---------------------------------------------------------------------------
// Combine: block (n, slice of 128 d). Also writes the mask output
// (slice covers t = sl*512 + tid*4 .. +3).
// ---------------------------------------------------------------------------
__global__ __launch_bounds__(128) void ctx_combine_kernel(
    const float* __restrict__ part, const float* __restrict__ ms,
    const int* __restrict__ lens, const int* __restrict__ pfx,
    float* __restrict__ ctx, float* __restrict__ mask_out) {
  const int n = blockIdx.x >> 2;
  const int sl = blockIdx.x & 3;
  const int tid = threadIdx.x;
  const int len = lens[n];

  // Mask: 4 slices x 128 threads x float4 = 2048 floats per row.
  {
    const int tb = sl * 512 + tid * 4;
    float4 mv;
    mv.x = (tb + 0 >= len) ? 1.0f : 0.0f;
    mv.y = (tb + 1 >= len) ? 1.0f : 0.0f;
    mv.z = (tb + 2 >= len) ? 1.0f : 0.0f;
    mv.w = (tb + 3 >= len) ? 1.0f : 0.0f;
    ((float4*)(mask_out + (size_t)n * T_DIM))[sl * 128 + tid] = mv;
  }

  const int nc = (len + TCHUNK - 1) >> 6;  // >= 1
  const int base = pfx[n];

  float M = -INFINITY;
  for (int c = 0; c < nc; ++c) M = fmaxf(M, ms[(base + c) * 2]);
  float S = 0.0f;
  for (int c = 0; c < nc; ++c)
    S += ms[(base + c) * 2 + 1] * __expf(ms[(base + c) * 2] - M);
  const float invS = 1.0f / S;

  const int d = sl * 128 + tid;
  float acc = 0.0f;
  for (int c = 0; c < nc; ++c)
    acc = fmaf(__expf(ms[(base + c) * 2] - M) * invS,
               part[(size_t)(base + c) * D_DIM + d], acc);
  ctx[(size_t)n * D_DIM + d] = acc;
}

extern "C" void kernel_launch(void* const* d_in, const int* in_sizes, int n_in,
                              void* d_out, int out_size, void* d_ws, size_t ws_size,
                              hipStream_t stream) {
  const float* Q = (const float*)d_in[0];     // [128][512]
  const float* K = (const float*)d_in[1];     // [128][2048][512]
  const float* V = (const float*)d_in[2];     // [128][2048][512]
  const int* lens = (const int*)d_in[3];      // [128]

  float* out = (float*)d_out;
  float* ctx = out;                           // [128][512]
  float* mask_out = out + N_DIM * D_DIM;      // [128][2048]

  float* part = (float*)d_ws;                 // [MAXBLK][512] (8 MB)
  float* ms = part + (size_t)MAXBLK * D_DIM;  // [MAXBLK][2]
  int* pfx = (int*)(ms + (size_t)MAXBLK * 2); // [129]

  prep_kernel<<<dim3(1), 128, 0, stream>>>(lens, pfx);
  fused_attn_kernel<<<dim3(MAXBLK), 256, 0, stream>>>(Q, K, V, lens, pfx, part, ms);
  ctx_combine_kernel<<<dim3(N_DIM * 4), 128, 0, stream>>>(part, ms, lens, pfx, ctx, mask_out);
}

// Round 5
// 125.237 us; speedup vs baseline: 1.1865x; 1.0456x over previous
//
#include <hip/hip_runtime.h>
#include <math.h>

// Single-query attention, N=128, T=2048, D=512, fp32, length-masked.
// Masked t >= len: energy -1e9 -> expf == 0 exactly -> skip K/V reads there.
//
// R5: (1) pair-row streaming per wave (rows 2w,2w+1, step 8): 4 KB contiguous
// bursts, 2 interleaved reduces, 8 prefetch loads in flight; (2) prefix-scan
// folded into the fused kernel (prep kernel and its launch gap removed);
// block 0 publishes pfx for the combine kernel. (3) launch_bounds(256,4).

#define N_DIM 128
#define T_DIM 2048
#define D_DIM 512
#define TCHUNK 64
#define MAXBLK (N_DIM * (T_DIM / TCHUNK))  // 4096 worst-case chunks

__device__ __forceinline__ float dot8(const float4 q0, const float4 q1,
                                      const float4 k0, const float4 k1) {
  return q0.x * k0.x + q0.y * k0.y + q0.z * k0.z + q0.w * k0.w +
         q1.x * k1.x + q1.y * k1.y + q1.z * k1.z + q1.w * k1.w;
}

__global__ __launch_bounds__(256, 4) void fused_attn_kernel(
    const float* __restrict__ Q, const float* __restrict__ K,
    const float* __restrict__ V, const int* __restrict__ lens,
    float* __restrict__ part, float* __restrict__ ms,
    int* __restrict__ pfx_out) {
  const int tid = threadIdx.x;
  const int b = blockIdx.x;

  // ---- In-block prefix scan of per-batch chunk counts (redundant per block).
  __shared__ int pfxL[N_DIM + 1];
  __shared__ int scanS[N_DIM];
  if (tid < N_DIM) scanS[tid] = (lens[tid] + TCHUNK - 1) >> 6;
  __syncthreads();
  for (int off = 1; off < N_DIM; off <<= 1) {
    int t = 0;
    if (tid < N_DIM && tid >= off) t = scanS[tid - off];
    __syncthreads();
    if (tid < N_DIM) scanS[tid] += t;
    __syncthreads();
  }
  if (tid < N_DIM) pfxL[tid + 1] = scanS[tid];
  if (tid == 0) pfxL[0] = 0;
  __syncthreads();

  const int total = pfxL[N_DIM];
  if (b == 0 && tid <= N_DIM) pfx_out[tid] = pfxL[tid];
  if (b >= total) return;

  // ---- Map b -> (n, c) via binary search on LDS pfx (uniform, broadcast).
  int lo = 0, hi = N_DIM;
  while (hi - lo > 1) {
    const int mid = (lo + hi) >> 1;
    if (pfxL[mid] <= b) lo = mid; else hi = mid;
  }
  const int n = lo;
  const int c = b - pfxL[lo];
  const int len = lens[n];
  const int t0 = c * TCHUNK;
  const int nvalid = min(TCHUNK, len - t0);  // >= 1

  const int lane = tid & 63;
  const int wave = tid >> 6;

  const float4* Qv = (const float4*)(Q + (size_t)n * D_DIM);
  const float4 q0 = Qv[lane];
  const float4 q1 = Qv[64 + lane];
  const float4* Kb = (const float4*)(K + ((size_t)n * T_DIM + t0) * D_DIM);
  const float4* Vb = (const float4*)(V + ((size_t)n * T_DIM + t0) * D_DIM);

  float m = -INFINITY, ssum = 0.0f;
  float4 a0 = make_float4(0.f, 0.f, 0.f, 0.f);
  float4 a1 = make_float4(0.f, 0.f, 0.f, 0.f);

  // Wave handles row pairs (tt, tt+1), tt = 2*wave, step 8. 4 KB contiguous
  // per array per iteration; 1-pair-deep prefetch (8 loads in flight).
  int tt = 2 * wave;
  float4 ka0, ka1, kb0, kb1, va0, va1, vb0, vb1;
  if (tt < nvalid) {
    const size_t o = (size_t)tt * 128;
    ka0 = Kb[o + lane];       ka1 = Kb[o + 64 + lane];
    kb0 = Kb[o + 128 + lane]; kb1 = Kb[o + 192 + lane];
    va0 = Vb[o + lane];       va1 = Vb[o + 64 + lane];
    vb0 = Vb[o + 128 + lane]; vb1 = Vb[o + 192 + lane];
  }
  for (; tt < nvalid; tt += 8) {
    const bool pre = (tt + 8 < nvalid);  // wave-uniform
    float4 nka0, nka1, nkb0, nkb1, nva0, nva1, nvb0, nvb1;
    if (pre) {
      const size_t o = (size_t)(tt + 8) * 128;
      nka0 = Kb[o + lane];       nka1 = Kb[o + 64 + lane];
      nkb0 = Kb[o + 128 + lane]; nkb1 = Kb[o + 192 + lane];
      nva0 = Vb[o + lane];       nva1 = Vb[o + 64 + lane];
      nvb0 = Vb[o + 128 + lane]; nvb1 = Vb[o + 192 + lane];
    }

    float eA = dot8(q0, q1, ka0, ka1);
    float eB = dot8(q0, q1, kb0, kb1);
#pragma unroll
    for (int off = 32; off; off >>= 1) {
      eA += __shfl_xor(eA, off, 64);
      eB += __shfl_xor(eB, off, 64);
    }
    if (tt + 1 >= nvalid) eB = -INFINITY;  // half-pair at chunk tail

    // Branch-free online-softmax update (eA finite -> no inf-inf NaN).
    const float mNew = fmaxf(m, fmaxf(eA, eB));
    const float sc = __expf(m - mNew);     // first iter: expf(-inf) = 0
    const float pA = __expf(eA - mNew);
    const float pB = __expf(eB - mNew);    // eB=-inf -> 0
    m = mNew;
    ssum = ssum * sc + pA + pB;
    a0.x = a0.x * sc + pA * va0.x + pB * vb0.x;
    a0.y = a0.y * sc + pA * va0.y + pB * vb0.y;
    a0.z = a0.z * sc + pA * va0.z + pB * vb0.z;
    a0.w = a0.w * sc + pA * va0.w + pB * vb0.w;
    a1.x = a1.x * sc + pA * va1.x + pB * vb1.x;
    a1.y = a1.y * sc + pA * va1.y + pB * vb1.y;
    a1.z = a1.z * sc + pA * va1.z + pB * vb1.z;
    a1.w = a1.w * sc + pA * va1.w + pB * vb1.w;

    if (pre) {
      ka0 = nka0; ka1 = nka1; kb0 = nkb0; kb1 = nkb1;
      va0 = nva0; va1 = nva1; vb0 = nvb0; vb1 = nvb1;
    }
  }

  // ---- Cross-wave combine (one barrier). Waves with no rows: m=-inf, s=0.
  __shared__ float accL[4 * D_DIM];  // [wave][d], 8 KB
  __shared__ float mL[4], sL[4];
  ((float4*)accL)[wave * 128 + lane] = a0;
  ((float4*)accL)[wave * 128 + 64 + lane] = a1;
  if (lane == 0) { mL[wave] = m; sL[wave] = ssum; }
  __syncthreads();

  const float M = fmaxf(fmaxf(mL[0], mL[1]), fmaxf(mL[2], mL[3]));  // finite
  const float c0 = __expf(mL[0] - M), c1 = __expf(mL[1] - M);
  const float c2 = __expf(mL[2] - M), c3 = __expf(mL[3] - M);
  const float S = sL[0] * c0 + sL[1] * c1 + sL[2] * c2 + sL[3] * c3;

  const int d = tid * 2;
  float2 r;
  r.x = c0 * accL[0 * D_DIM + d] + c1 * accL[1 * D_DIM + d] +
        c2 * accL[2 * D_DIM + d] + c3 * accL[3 * D_DIM + d];
  r.y = c0 * accL[0 * D_DIM + d + 1] + c1 * accL[1 * D_DIM + d + 1] +
        c2 * accL[2 * D_DIM + d + 1] + c3 * accL[3 * D_DIM + d + 1];
  ((float2*)(part + (size_t)b * D_DIM))[tid] = r;
  if (tid == 0) { ms[b * 2] = M; ms[b * 2 + 1] = S; }
}

// ---------------------------------------------------------------------------
// Combine: block (n, slice of 128 d); also writes mask floats.
// ---------------------------------------------------------------------------
__global__ __launch_bounds__(128) void ctx_combine_kernel(
    const float* __restrict__ part, const float* __restrict__ ms,
    const int* __restrict__ lens, const int* __restrict__ pfx,
    float* __restrict__ ctx, float* __restrict__ mask_out) {
  const int n = blockIdx.x >> 2;
  const int sl = blockIdx.x & 3;
  const int tid = threadIdx.x;
  const int len = lens[n];

  {
    const int tb = sl * 512 + tid * 4;
    float4 mv;
    mv.x = (tb + 0 >= len) ? 1.0f : 0.0f;
    mv.y = (tb + 1 >= len) ? 1.0f : 0.0f;
    mv.z = (tb + 2 >= len) ? 1.0f : 0.0f;
    mv.w = (tb + 3 >= len) ? 1.0f : 0.0f;
    ((float4*)(mask_out + (size_t)n * T_DIM))[sl * 128 + tid] = mv;
  }

  const int nc = (len + TCHUNK - 1) >> 6;  // >= 1
  const int base = pfx[n];

  float M = -INFINITY;
  for (int c = 0; c < nc; ++c) M = fmaxf(M, ms[(base + c) * 2]);
  float S = 0.0f;
  for (int c = 0; c < nc; ++c)
    S += ms[(base + c) * 2 + 1] * __expf(ms[(base + c) * 2] - M);
  const float invS = 1.0f / S;

  const int d = sl * 128 + tid;
  float acc = 0.0f;
  for (int c = 0; c < nc; ++c)
    acc = fmaf(__expf(ms[(base + c) * 2] - M) * invS,
               part[(size_t)(base + c) * D_DIM + d], acc);
  ctx[(size_t)n * D_DIM + d] = acc;
}

extern "C" void kernel_launch(void* const* d_in, const int* in_sizes, int n_in,
                              void* d_out, int out_size, void* d_ws, size_t ws_size,
                              hipStream_t stream) {
  const float* Q = (const float*)d_in[0];     // [128][512]
  const float* K = (const float*)d_in[1];     // [128][2048][512]
  const float* V = (const float*)d_in[2];     // [128][2048][512]
  const int* lens = (const int*)d_in[3];      // [128]

  float* out = (float*)d_out;
  float* ctx = out;                           // [128][512]
  float* mask_out = out + N_DIM * D_DIM;      // [128][2048]

  float* part = (float*)d_ws;                 // [MAXBLK][512] (8 MB)
  float* ms = part + (size_t)MAXBLK * D_DIM;  // [MAXBLK][2]
  int* pfx = (int*)(ms + (size_t)MAXBLK * 2); // [129]

  fused_attn_kernel<<<dim3(MAXBLK), 256, 0, stream>>>(Q, K, V, lens, part, ms, pfx);
  ctx_combine_kernel<<<dim3(N_DIM * 4), 128, 0, stream>>>(part, ms, lens, pfx, ctx, mask_out);
}